// Round 8
// baseline (849.053 us; speedup 1.0000x reference)
//
#include <hip/hip_runtime.h>
#include <math.h>

typedef __attribute__((ext_vector_type(8)))  short s16x8;   // 8 bf16 (4 VGPRs)
typedef __attribute__((ext_vector_type(16))) float f32x16;  // MFMA 32x32 acc

__device__ inline float bf_lo(unsigned u) { return __uint_as_float(u << 16); }
__device__ inline float bf_hi(unsigned u) { return __uint_as_float(u & 0xffff0000u); }
__device__ inline unsigned short f2bf(float f) {           // RNE f32 -> bf16
    unsigned u = __float_as_uint(f);
    u += 0x7fffu + ((u >> 16) & 1u);
    return (unsigned short)(u >> 16);
}

// ===========================================================================
// Fused prep: x f32->bf16, 6 weight transposes ([K][Nc] f32 -> [Np][K] bf16,
// zero-padded), deg zeroing. One dispatch instead of 8.
// ===========================================================================
__global__ __launch_bounds__(256)
void prep_fused(const float* __restrict__ x,   unsigned short* __restrict__ xbf,
                const float* __restrict__ W1a, unsigned short* __restrict__ W1aT,
                const float* __restrict__ W1b, unsigned short* __restrict__ W1bT,
                const float* __restrict__ W2a, unsigned short* __restrict__ W2aT,
                const float* __restrict__ W2b, unsigned short* __restrict__ W2bT,
                const float* __restrict__ W3a, unsigned short* __restrict__ W3aT,
                const float* __restrict__ W3b, unsigned short* __restrict__ W3bT,
                int* __restrict__ deg, int N) {
    int i = blockIdx.x * 256 + threadIdx.x;
    int nx = N * 48;
    if (i < nx) { xbf[i] = f2bf(x[i]); return; }
    i -= nx;
    if (i < N) { deg[i] = 0; return; }
    i -= N;
    if (i < 256 * 96)  { int n = i / 96,  k = i - n * 96;  W1aT[i] = f2bf(W1a[(size_t)k * 256 + n]); return; }
    i -= 256 * 96;
    if (i < 128 * 256) { int n = i / 256, k = i - n * 256; W1bT[i] = f2bf(W1b[(size_t)k * 128 + n]); return; }
    i -= 128 * 256;
    if (i < 256 * 304) { int n = i / 304, k = i - n * 304; W2aT[i] = f2bf(W2a[(size_t)k * 256 + n]); return; }
    i -= 256 * 304;
    if (i < 128 * 256) { int n = i / 256, k = i - n * 256; W2bT[i] = f2bf(W2b[(size_t)k * 128 + n]); return; }
    i -= 128 * 256;
    if (i < 256 * 304) { int n = i / 304, k = i - n * 304; W3aT[i] = f2bf(W3a[(size_t)k * 256 + n]); return; }
    i -= 256 * 304;
    if (i < 64 * 256)  { int n = i / 256, k = i - n * 256;
                         float v = (n < 40) ? W3b[(size_t)k * 40 + n] : 0.f;
                         W3bT[i] = f2bf(v); return; }
}

// ===========================================================================
// CSR build (by dst)
// ===========================================================================
__global__ __launch_bounds__(256)
void deg_hist(const int* __restrict__ dst, int* __restrict__ deg, int E) {
    int i = blockIdx.x * 256 + threadIdx.x;
    if (i < E) atomicAdd(&deg[dst[i]], 1);
}

__global__ __launch_bounds__(256)
void scan_block_sums(const int* __restrict__ deg, int* __restrict__ bsum, int N) {
    __shared__ int sh[256];
    int base = blockIdx.x * 1024 + threadIdx.x * 4;
    int s = 0;
    #pragma unroll
    for (int k = 0; k < 4; ++k) { int i = base + k; if (i < N) s += deg[i]; }
    sh[threadIdx.x] = s;
    __syncthreads();
    for (int off = 128; off >= 1; off >>= 1) {
        if (threadIdx.x < off) sh[threadIdx.x] += sh[threadIdx.x + off];
        __syncthreads();
    }
    if (threadIdx.x == 0) bsum[blockIdx.x] = sh[0];
}

__global__ __launch_bounds__(256)
void scan_bsums(int* __restrict__ bsum, int nb) {
    __shared__ int sh[256];
    int t = threadIdx.x;
    int v = (t < nb) ? bsum[t] : 0;
    sh[t] = v;
    __syncthreads();
    for (int off = 1; off < 256; off <<= 1) {
        int add = (t >= off) ? sh[t - off] : 0;
        __syncthreads();
        sh[t] += add;
        __syncthreads();
    }
    if (t < nb) bsum[t] = sh[t] - v;
}

__global__ __launch_bounds__(256)
void scan_finalize(const int* __restrict__ deg, const int* __restrict__ bsum,
                   int* __restrict__ rowptr, int N) {
    __shared__ int sh[256];
    int t = threadIdx.x;
    int base = blockIdx.x * 1024 + t * 4;
    int loc[4];
    int s = 0;
    #pragma unroll
    for (int k = 0; k < 4; ++k) {
        int i = base + k;
        loc[k] = (i < N) ? deg[i] : 0;
        s += loc[k];
    }
    sh[t] = s;
    __syncthreads();
    for (int off = 1; off < 256; off <<= 1) {
        int add = (t >= off) ? sh[t - off] : 0;
        __syncthreads();
        sh[t] += add;
        __syncthreads();
    }
    int run = bsum[blockIdx.x] + sh[t] - s;
    #pragma unroll
    for (int k = 0; k < 4; ++k) {
        int i = base + k;
        if (i < N) rowptr[i] = run;
        run += loc[k];
    }
}

// ===========================================================================
// Block-owned scatter: 256 blocks, block b owns nodes [b*per, b*per+per).
// LDS cursors (init from rowptr, fresh every launch -> replay-safe, zero
// global atomics). Each block scans the FULL dst array coalesced (int4) and
// places only its own nodes' edges -> each csr 64B line has exactly ONE
// writer block (no cross-XCD line bouncing, which round-7 counters showed
// phasing cannot fix: WRITE_SIZE stayed 91MB for a 6.4MB payload).
// ===========================================================================
__global__ __launch_bounds__(512)
void csr_scatter_owned(const int* __restrict__ src, const int* __restrict__ dst,
                       const int* __restrict__ rowptr,
                       int* __restrict__ csr_src, int E, int N, int per) {
    __shared__ int curs[512];               // per <= 512 enforced by host
    const int lo  = blockIdx.x * per;
    const int hi  = min(lo + per, N);
    const int cnt = hi - lo;
    if (cnt <= 0) return;
    for (int t = threadIdx.x; t < cnt; t += 512)
        curs[t] = rowptr[lo + t];
    __syncthreads();

    const int nq = E >> 2;                  // E divisible by 4 in practice
    const int4* dst4 = (const int4*)dst;
    for (int q = threadIdx.x; q < nq; q += 512) {
        const int4 d4 = dst4[q];
        const int e = q * 4;
        if (d4.x >= lo && d4.x < hi) { int p = atomicAdd(&curs[d4.x - lo], 1); csr_src[p] = src[e + 0]; }
        if (d4.y >= lo && d4.y < hi) { int p = atomicAdd(&curs[d4.y - lo], 1); csr_src[p] = src[e + 1]; }
        if (d4.z >= lo && d4.z < hi) { int p = atomicAdd(&curs[d4.z - lo], 1); csr_src[p] = src[e + 2]; }
        if (d4.w >= lo && d4.w < hi) { int p = atomicAdd(&curs[d4.w - lo], 1); csr_src[p] = src[e + 3]; }
    }
    // tail (E % 4)
    for (int e = nq * 4 + threadIdx.x; e < E; e += 512) {
        int d = dst[e];
        if (d >= lo && d < hi) { int p = atomicAdd(&curs[d - lo], 1); csr_src[p] = src[e]; }
    }
}

// ===========================================================================
// LGConv gather, bf16 in/out, f32 accumulate. 8 channels (16B) per lane.
// ===========================================================================
template<int D, int LPN>
__global__ __launch_bounds__(256)
void lgconv_gather_bf16(const unsigned short* __restrict__ x,
                        const int* __restrict__ rowptr,
                        const int* __restrict__ deg,
                        const int* __restrict__ csr_src,
                        unsigned short* __restrict__ out, int N) {
    const int g    = (blockIdx.x * 256 + threadIdx.x) / LPN;
    const int lane = threadIdx.x & (LPN - 1);
    if (g >= N) return;
    if (lane * 8 >= D) return;
    const int start = rowptr[g];
    const int dg    = deg[g];
    float acc[8] = {0.f,0.f,0.f,0.f,0.f,0.f,0.f,0.f};
    int j = 0;
    for (; j + 1 < dg; j += 2) {
        int s0 = csr_src[start + j];
        int s1 = csr_src[start + j + 1];
        uint4 v0 = *(const uint4*)(x + (size_t)s0 * D + lane * 8);
        uint4 v1 = *(const uint4*)(x + (size_t)s1 * D + lane * 8);
        acc[0] += bf_lo(v0.x); acc[1] += bf_hi(v0.x);
        acc[2] += bf_lo(v0.y); acc[3] += bf_hi(v0.y);
        acc[4] += bf_lo(v0.z); acc[5] += bf_hi(v0.z);
        acc[6] += bf_lo(v0.w); acc[7] += bf_hi(v0.w);
        acc[0] += bf_lo(v1.x); acc[1] += bf_hi(v1.x);
        acc[2] += bf_lo(v1.y); acc[3] += bf_hi(v1.y);
        acc[4] += bf_lo(v1.z); acc[5] += bf_hi(v1.z);
        acc[6] += bf_lo(v1.w); acc[7] += bf_hi(v1.w);
    }
    if (j < dg) {
        int s0 = csr_src[start + j];
        uint4 v0 = *(const uint4*)(x + (size_t)s0 * D + lane * 8);
        acc[0] += bf_lo(v0.x); acc[1] += bf_hi(v0.x);
        acc[2] += bf_lo(v0.y); acc[3] += bf_hi(v0.y);
        acc[4] += bf_lo(v0.z); acc[5] += bf_hi(v0.z);
        acc[6] += bf_lo(v0.w); acc[7] += bf_hi(v0.w);
    }
    uint4 o;
    o.x = ((unsigned)f2bf(acc[1]) << 16) | f2bf(acc[0]);
    o.y = ((unsigned)f2bf(acc[3]) << 16) | f2bf(acc[2]);
    o.z = ((unsigned)f2bf(acc[5]) << 16) | f2bf(acc[4]);
    o.w = ((unsigned)f2bf(acc[7]) << 16) | f2bf(acc[6]);
    *(uint4*)(out + (size_t)g * D + lane * 8) = o;
}

// ===========================================================================
// Fused 2-layer MLP, bf16 MFMA (32x32x16), 64 rows/block, 4 waves.
// (unchanged from round 4/7 — verified correct, absmax 2.0)
// ===========================================================================
template<int LA, int LB, int LC, bool LSM>
__global__ __launch_bounds__(256)
void fused_mlp_mfma(const unsigned short* __restrict__ segA,
                    const unsigned short* __restrict__ segB,
                    const unsigned short* __restrict__ segC,
                    const unsigned short* __restrict__ WaT, const float* __restrict__ ba,
                    const unsigned short* __restrict__ WbT, const float* __restrict__ bb,
                    void* __restrict__ outv, int n) {
    constexpr int K1  = LA + LB + LC;       // 96 or 304
    constexpr int NS1 = K1 / 16;
    constexpr int K2P = 264;                // 256 + 8 (rows stay 16B-aligned)
    __shared__ __attribute__((aligned(16))) unsigned short hid[64 * K2P];

    const int tid  = threadIdx.x;
    const int wave = tid >> 6;
    const int lane = tid & 63;
    const int l31  = lane & 31;
    const int lh   = lane >> 5;
    const int row0 = blockIdx.x * 64;

    const int r0  = row0 + l31;
    const int r1  = r0 + 32;
    const int ra0 = (r0 < n) ? r0 : (n - 1);
    const int ra1 = (r1 < n) ? r1 : (n - 1);

    // ---------------- stage 1 ----------------
    f32x16 acc00 = {}, acc01 = {}, acc10 = {}, acc11 = {};
    const unsigned short* wa0 = WaT + (size_t)(wave * 64 + l31) * K1 + lh * 8;
    const unsigned short* wa1 = wa0 + (size_t)32 * K1;

    #pragma unroll
    for (int s = 0; s < NS1; ++s) {
        const int k0 = s * 16;              // compile-time; segment-uniform
        const unsigned short* ap;
        int strd, off;
        if (k0 < LA)           { ap = segA; strd = LA; off = k0; }
        else if (k0 < LA + LB) { ap = segB; strd = LB; off = k0 - LA; }
        else                   { ap = segC; strd = LC; off = k0 - LA - LB; }
        s16x8 a0 = *(const s16x8*)(ap + (size_t)ra0 * strd + off + lh * 8);
        s16x8 a1 = *(const s16x8*)(ap + (size_t)ra1 * strd + off + lh * 8);
        s16x8 b0 = *(const s16x8*)(wa0 + k0);
        s16x8 b1 = *(const s16x8*)(wa1 + k0);
        acc00 = __builtin_amdgcn_mfma_f32_32x32x16_bf16(a0, b0, acc00, 0, 0, 0);
        acc01 = __builtin_amdgcn_mfma_f32_32x32x16_bf16(a0, b1, acc01, 0, 0, 0);
        acc10 = __builtin_amdgcn_mfma_f32_32x32x16_bf16(a1, b0, acc10, 0, 0, 0);
        acc11 = __builtin_amdgcn_mfma_f32_32x32x16_bf16(a1, b1, acc11, 0, 0, 0);
    }

    // epilogue: + bias, relu -> hid[m][k] bf16
    {
        const int c0 = wave * 64 + l31;
        const int c1 = c0 + 32;
        const float bias0 = ba[c0];
        const float bias1 = ba[c1];
        #pragma unroll
        for (int t = 0; t < 16; ++t) {
            int rloc = (t & 3) + 8 * (t >> 2) + 4 * lh;
            hid[rloc * K2P + c0]        = f2bf(fmaxf(acc00[t] + bias0, 0.f));
            hid[rloc * K2P + c1]        = f2bf(fmaxf(acc01[t] + bias1, 0.f));
            hid[(rloc + 32) * K2P + c0] = f2bf(fmaxf(acc10[t] + bias0, 0.f));
            hid[(rloc + 32) * K2P + c1] = f2bf(fmaxf(acc11[t] + bias1, 0.f));
        }
    }
    __syncthreads();

    // ---------------- stage 2 ----------------
    if (!LSM) {
        f32x16 d0 = {}, d1 = {};
        const unsigned short* wb = WbT + (size_t)(wave * 32 + l31) * 256 + lh * 8;
        const int h0 = l31 * K2P + lh * 8;
        #pragma unroll
        for (int s = 0; s < 16; ++s) {
            s16x8 a0 = *(const s16x8*)&hid[h0 + s * 16];
            s16x8 a1 = *(const s16x8*)&hid[h0 + 32 * K2P + s * 16];
            s16x8 b  = *(const s16x8*)(wb + s * 16);
            d0 = __builtin_amdgcn_mfma_f32_32x32x16_bf16(a0, b, d0, 0, 0, 0);
            d1 = __builtin_amdgcn_mfma_f32_32x32x16_bf16(a1, b, d1, 0, 0, 0);
        }
        const int col = wave * 32 + l31;
        const float bias = bb[col];
        unsigned short* out = (unsigned short*)outv;
        #pragma unroll
        for (int t = 0; t < 16; ++t) {
            int rloc = (t & 3) + 8 * (t >> 2) + 4 * lh;
            int rr0 = row0 + rloc, rr1 = rr0 + 32;
            if (rr0 < n) out[(size_t)rr0 * 128 + col] = f2bf(fmaxf(d0[t] + bias, 0.f));
            if (rr1 < n) out[(size_t)rr1 * 128 + col] = f2bf(fmaxf(d1[t] + bias, 0.f));
        }
    } else {
        const int rt = wave & 1, ct = wave >> 1;
        f32x16 d = {};
        const unsigned short* wb = WbT + (size_t)(ct * 32 + l31) * 256 + lh * 8;
        const int h0 = (rt * 32 + l31) * K2P + lh * 8;
        #pragma unroll
        for (int s = 0; s < 16; ++s) {
            s16x8 a = *(const s16x8*)&hid[h0 + s * 16];
            s16x8 b = *(const s16x8*)(wb + s * 16);
            d = __builtin_amdgcn_mfma_f32_32x32x16_bf16(a, b, d, 0, 0, 0);
        }
        __syncthreads();                    // done reading hid; reuse as logits
        float* lg = (float*)hid;            // [64][68] f32 = 17.4KB <= 33.8KB
        const int col = ct * 32 + l31;
        const float bias = (col < 40) ? bb[col] : 0.f;
        #pragma unroll
        for (int t = 0; t < 16; ++t) {
            int rloc = rt * 32 + (t & 3) + 8 * (t >> 2) + 4 * lh;
            lg[rloc * 68 + col] = d[t] + bias;
        }
        __syncthreads();
        const int r = tid >> 2, j = tid & 3;
        float mx = -1e30f;
        #pragma unroll
        for (int c = 0; c < 10; ++c) mx = fmaxf(mx, lg[r * 68 + j * 10 + c]);
        mx = fmaxf(mx, __shfl_xor(mx, 1));
        mx = fmaxf(mx, __shfl_xor(mx, 2));
        float sm = 0.f;
        #pragma unroll
        for (int c = 0; c < 10; ++c) sm += __expf(lg[r * 68 + j * 10 + c] - mx);
        sm += __shfl_xor(sm, 1);
        sm += __shfl_xor(sm, 2);
        const float lse = mx + __logf(sm);
        const int row = row0 + r;
        float* out = (float*)outv;
        if (row < n) {
            #pragma unroll
            for (int c = 0; c < 10; ++c)
                out[(size_t)row * 40 + j * 10 + c] = lg[r * 68 + j * 10 + c] - lse;
        }
    }
}

// ===========================================================================
extern "C" void kernel_launch(void* const* d_in, const int* in_sizes, int n_in,
                              void* d_out, int out_size, void* d_ws, size_t ws_size,
                              hipStream_t stream) {
    const float* x   = (const float*)d_in[0];
    const int*   ei  = (const int*)d_in[1];
    const float* W1a = (const float*)d_in[2];
    const float* b1a = (const float*)d_in[3];
    const float* W1b = (const float*)d_in[4];
    const float* b1b = (const float*)d_in[5];
    const float* W2a = (const float*)d_in[6];
    const float* b2a = (const float*)d_in[7];
    const float* W2b = (const float*)d_in[8];
    const float* b2b = (const float*)d_in[9];
    const float* W3a = (const float*)d_in[10];
    const float* b3a = (const float*)d_in[11];
    const float* W3b = (const float*)d_in[12];
    const float* b3b = (const float*)d_in[13];
    float* out = (float*)d_out;

    const int E = in_sizes[1] / 2;
    const int N = in_sizes[0] / 48;
    const int* src = ei;
    const int* dst = ei + E;

    // ---- workspace carve-up (256B aligned) ----
    char* p = (char*)d_ws;
    auto alloc = [&](size_t bytes) { void* q = p; p += (bytes + 255) & ~(size_t)255; return q; };
    unsigned short* xbf  = (unsigned short*)alloc((size_t)N * 48  * 2);
    unsigned short* c1   = (unsigned short*)alloc((size_t)N * 48  * 2);
    unsigned short* h1   = (unsigned short*)alloc((size_t)N * 128 * 2);
    unsigned short* c2   = (unsigned short*)alloc((size_t)N * 128 * 2);  // also c3
    unsigned short* h2   = (unsigned short*)alloc((size_t)N * 128 * 2);
    unsigned short* W1aT = (unsigned short*)alloc((size_t)256 * 96  * 2);
    unsigned short* W1bT = (unsigned short*)alloc((size_t)128 * 256 * 2);
    unsigned short* W2aT = (unsigned short*)alloc((size_t)256 * 304 * 2);
    unsigned short* W2bT = (unsigned short*)alloc((size_t)128 * 256 * 2);
    unsigned short* W3aT = (unsigned short*)alloc((size_t)256 * 304 * 2);
    unsigned short* W3bT = (unsigned short*)alloc((size_t)64  * 256 * 2);
    int* deg     = (int*)alloc((size_t)N * 4);
    int* rowptr  = (int*)alloc((size_t)N * 4);
    int* bsum    = (int*)alloc(1024);
    int* csr_src = (int*)alloc((size_t)E * 4);

    const int nb_scan = (N + 1023) / 1024;
    const int nblk    = (N + 63) / 64;

    // ---- fused prep (x->bf16, 6 transposes, deg=0) ----
    {
        int total = N * 48 + N + 256*96 + 128*256 + 256*304 + 128*256 + 256*304 + 64*256;
        prep_fused<<<(total + 255) / 256, 256, 0, stream>>>(
            x, xbf, W1a, W1aT, W1b, W1bT, W2a, W2aT, W2b, W2bT,
            W3a, W3aT, W3b, W3bT, deg, N);
    }

    // ---- CSR build ----
    deg_hist<<<(E + 255) / 256, 256, 0, stream>>>(dst, deg, E);
    scan_block_sums<<<nb_scan, 256, 0, stream>>>(deg, bsum, N);
    scan_bsums<<<1, 256, 0, stream>>>(bsum, nb_scan);
    scan_finalize<<<nb_scan, 256, 0, stream>>>(deg, bsum, rowptr, N);
    {
        // owner blocks: per-block node range must fit the 512-entry LDS cursor
        int nown = 256;
        int per  = (N + nown - 1) / nown;
        while (per > 512) { nown *= 2; per = (N + nown - 1) / nown; }
        csr_scatter_owned<<<nown, 512, 0, stream>>>(src, dst, rowptr, csr_src, E, N, per);
    }

    // ---- layer 1 ----
    lgconv_gather_bf16<48, 8><<<((size_t)N * 8 + 255) / 256, 256, 0, stream>>>(
        xbf, rowptr, deg, csr_src, c1, N);
    fused_mlp_mfma<48, 48, 0, false><<<nblk, 256, 0, stream>>>(
        c1, xbf, (const unsigned short*)nullptr, W1aT, b1a, W1bT, b1b, h1, N);

    // ---- layer 2 ----
    lgconv_gather_bf16<128, 16><<<((size_t)N * 16 + 255) / 256, 256, 0, stream>>>(
        h1, rowptr, deg, csr_src, c2, N);
    fused_mlp_mfma<128, 128, 48, false><<<nblk, 256, 0, stream>>>(
        c2, h1, xbf, W2aT, b2a, W2bT, b2b, h2, N);

    // ---- layer 3 ----
    lgconv_gather_bf16<128, 16><<<((size_t)N * 16 + 255) / 256, 256, 0, stream>>>(
        h2, rowptr, deg, csr_src, c2, N);   // c3 reuses c2 slot
    fused_mlp_mfma<128, 128, 48, true><<<nblk, 256, 0, stream>>>(
        c2, h2, xbf, W3aT, b3a, W3bT, b3b, out, N);
}

// Round 9
// 571.273 us; speedup vs baseline: 1.4862x; 1.4862x over previous
//
#include <hip/hip_runtime.h>
#include <math.h>

typedef __attribute__((ext_vector_type(8)))  short s16x8;   // 8 bf16 (4 VGPRs)
typedef __attribute__((ext_vector_type(16))) float f32x16;  // MFMA 32x32 acc

__device__ inline float bf_lo(unsigned u) { return __uint_as_float(u << 16); }
__device__ inline float bf_hi(unsigned u) { return __uint_as_float(u & 0xffff0000u); }
__device__ inline unsigned short f2bf(float f) {           // RNE f32 -> bf16
    unsigned u = __float_as_uint(f);
    u += 0x7fffu + ((u >> 16) & 1u);
    return (unsigned short)(u >> 16);
}

// ===========================================================================
// Fused prep: x f32->bf16, 6 weight transposes ([K][Nc] f32 -> [Np][K] bf16,
// zero-padded), deg zeroing. One dispatch instead of 8.
// ===========================================================================
__global__ __launch_bounds__(256)
void prep_fused(const float* __restrict__ x,   unsigned short* __restrict__ xbf,
                const float* __restrict__ W1a, unsigned short* __restrict__ W1aT,
                const float* __restrict__ W1b, unsigned short* __restrict__ W1bT,
                const float* __restrict__ W2a, unsigned short* __restrict__ W2aT,
                const float* __restrict__ W2b, unsigned short* __restrict__ W2bT,
                const float* __restrict__ W3a, unsigned short* __restrict__ W3aT,
                const float* __restrict__ W3b, unsigned short* __restrict__ W3bT,
                int* __restrict__ deg, int N) {
    int i = blockIdx.x * 256 + threadIdx.x;
    int nx = N * 48;
    if (i < nx) { xbf[i] = f2bf(x[i]); return; }
    i -= nx;
    if (i < N) { deg[i] = 0; return; }
    i -= N;
    if (i < 256 * 96)  { int n = i / 96,  k = i - n * 96;  W1aT[i] = f2bf(W1a[(size_t)k * 256 + n]); return; }
    i -= 256 * 96;
    if (i < 128 * 256) { int n = i / 256, k = i - n * 256; W1bT[i] = f2bf(W1b[(size_t)k * 128 + n]); return; }
    i -= 128 * 256;
    if (i < 256 * 304) { int n = i / 304, k = i - n * 304; W2aT[i] = f2bf(W2a[(size_t)k * 256 + n]); return; }
    i -= 256 * 304;
    if (i < 128 * 256) { int n = i / 256, k = i - n * 256; W2bT[i] = f2bf(W2b[(size_t)k * 128 + n]); return; }
    i -= 128 * 256;
    if (i < 256 * 304) { int n = i / 304, k = i - n * 304; W3aT[i] = f2bf(W3a[(size_t)k * 256 + n]); return; }
    i -= 256 * 304;
    if (i < 64 * 256)  { int n = i / 256, k = i - n * 256;
                         float v = (n < 40) ? W3b[(size_t)k * 40 + n] : 0.f;
                         W3bT[i] = f2bf(v); return; }
}

// ===========================================================================
// CSR build (by dst). XCD-matched range ownership for the atomic kernels:
// block b -> edge slice (b>>3), dst range (b&7). Consecutive blockIdx
// round-robin across the 8 XCDs, so all blocks owning range r live on one
// XCD -> deg/cursor/csr lines for r are written by ONE XCD's L2 (no
// cross-XCD line bouncing; round-7 counters showed that was the bound).
// Mapping drift only affects speed, never correctness.
// ===========================================================================
__global__ __launch_bounds__(256)
void deg_hist_xcd(const int* __restrict__ dst, int* __restrict__ deg,
                  int E, int N) {
    const int r     = blockIdx.x & 7;
    const int sb    = blockIdx.x >> 3;
    const int nsl   = gridDim.x >> 3;
    const int chunk = (N + 7) / 8;
    const int lo = r * chunk;
    const int hi = min(lo + chunk, N);
    const int nq = E >> 2;
    const int4* dst4 = (const int4*)dst;
    for (int q = sb * 256 + threadIdx.x; q < nq; q += nsl * 256) {
        const int4 d4 = dst4[q];
        if (d4.x >= lo && d4.x < hi) atomicAdd(&deg[d4.x], 1);
        if (d4.y >= lo && d4.y < hi) atomicAdd(&deg[d4.y], 1);
        if (d4.z >= lo && d4.z < hi) atomicAdd(&deg[d4.z], 1);
        if (d4.w >= lo && d4.w < hi) atomicAdd(&deg[d4.w], 1);
    }
    if (sb == 0) {
        for (int e = nq * 4 + threadIdx.x; e < E; e += 256) {
            int d = dst[e];
            if (d >= lo && d < hi) atomicAdd(&deg[d], 1);
        }
    }
}

__global__ __launch_bounds__(256)
void scan_block_sums(const int* __restrict__ deg, int* __restrict__ bsum, int N) {
    __shared__ int sh[256];
    int base = blockIdx.x * 1024 + threadIdx.x * 4;
    int s = 0;
    #pragma unroll
    for (int k = 0; k < 4; ++k) { int i = base + k; if (i < N) s += deg[i]; }
    sh[threadIdx.x] = s;
    __syncthreads();
    for (int off = 128; off >= 1; off >>= 1) {
        if (threadIdx.x < off) sh[threadIdx.x] += sh[threadIdx.x + off];
        __syncthreads();
    }
    if (threadIdx.x == 0) bsum[blockIdx.x] = sh[0];
}

__global__ __launch_bounds__(256)
void scan_bsums(int* __restrict__ bsum, int nb) {
    __shared__ int sh[256];
    int t = threadIdx.x;
    int v = (t < nb) ? bsum[t] : 0;
    sh[t] = v;
    __syncthreads();
    for (int off = 1; off < 256; off <<= 1) {
        int add = (t >= off) ? sh[t - off] : 0;
        __syncthreads();
        sh[t] += add;
        __syncthreads();
    }
    if (t < nb) bsum[t] = sh[t] - v;
}

__global__ __launch_bounds__(256)
void scan_finalize(const int* __restrict__ deg, const int* __restrict__ bsum,
                   int* __restrict__ rowptr, int* __restrict__ cursor, int N) {
    __shared__ int sh[256];
    int t = threadIdx.x;
    int base = blockIdx.x * 1024 + t * 4;
    int loc[4];
    int s = 0;
    #pragma unroll
    for (int k = 0; k < 4; ++k) {
        int i = base + k;
        loc[k] = (i < N) ? deg[i] : 0;
        s += loc[k];
    }
    sh[t] = s;
    __syncthreads();
    for (int off = 1; off < 256; off <<= 1) {
        int add = (t >= off) ? sh[t - off] : 0;
        __syncthreads();
        sh[t] += add;
        __syncthreads();
    }
    int run = bsum[blockIdx.x] + sh[t] - s;
    #pragma unroll
    for (int k = 0; k < 4; ++k) {
        int i = base + k;
        if (i < N) { rowptr[i] = run; cursor[i] = run; }
        run += loc[k];
    }
}

__global__ __launch_bounds__(256)
void csr_scatter_xcd(const int* __restrict__ src, const int* __restrict__ dst,
                     int* __restrict__ cursor, int* __restrict__ csr_src,
                     int E, int N) {
    const int r     = blockIdx.x & 7;
    const int sb    = blockIdx.x >> 3;
    const int nsl   = gridDim.x >> 3;
    const int chunk = (N + 7) / 8;
    const int lo = r * chunk;
    const int hi = min(lo + chunk, N);
    const int nq = E >> 2;
    const int4* dst4 = (const int4*)dst;
    for (int q = sb * 256 + threadIdx.x; q < nq; q += nsl * 256) {
        const int4 d4 = dst4[q];
        const int e = q * 4;
        if (d4.x >= lo && d4.x < hi) { int p = atomicAdd(&cursor[d4.x], 1); if (p < E) csr_src[p] = src[e + 0]; }
        if (d4.y >= lo && d4.y < hi) { int p = atomicAdd(&cursor[d4.y], 1); if (p < E) csr_src[p] = src[e + 1]; }
        if (d4.z >= lo && d4.z < hi) { int p = atomicAdd(&cursor[d4.z], 1); if (p < E) csr_src[p] = src[e + 2]; }
        if (d4.w >= lo && d4.w < hi) { int p = atomicAdd(&cursor[d4.w], 1); if (p < E) csr_src[p] = src[e + 3]; }
    }
    if (sb == 0) {
        for (int e = nq * 4 + threadIdx.x; e < E; e += 256) {
            int d = dst[e];
            if (d >= lo && d < hi) { int p = atomicAdd(&cursor[d], 1); if (p < E) csr_src[p] = src[e]; }
        }
    }
}

// ===========================================================================
// LGConv gather, bf16 in/out, f32 accumulate. 8 channels (16B) per lane.
// ===========================================================================
template<int D, int LPN>
__global__ __launch_bounds__(256)
void lgconv_gather_bf16(const unsigned short* __restrict__ x,
                        const int* __restrict__ rowptr,
                        const int* __restrict__ deg,
                        const int* __restrict__ csr_src,
                        unsigned short* __restrict__ out, int N) {
    const int g    = (blockIdx.x * 256 + threadIdx.x) / LPN;
    const int lane = threadIdx.x & (LPN - 1);
    if (g >= N) return;
    if (lane * 8 >= D) return;
    const int start = rowptr[g];
    const int dg    = deg[g];
    float acc[8] = {0.f,0.f,0.f,0.f,0.f,0.f,0.f,0.f};
    int j = 0;
    for (; j + 1 < dg; j += 2) {
        int s0 = csr_src[start + j];
        int s1 = csr_src[start + j + 1];
        uint4 v0 = *(const uint4*)(x + (size_t)s0 * D + lane * 8);
        uint4 v1 = *(const uint4*)(x + (size_t)s1 * D + lane * 8);
        acc[0] += bf_lo(v0.x); acc[1] += bf_hi(v0.x);
        acc[2] += bf_lo(v0.y); acc[3] += bf_hi(v0.y);
        acc[4] += bf_lo(v0.z); acc[5] += bf_hi(v0.z);
        acc[6] += bf_lo(v0.w); acc[7] += bf_hi(v0.w);
        acc[0] += bf_lo(v1.x); acc[1] += bf_hi(v1.x);
        acc[2] += bf_lo(v1.y); acc[3] += bf_hi(v1.y);
        acc[4] += bf_lo(v1.z); acc[5] += bf_hi(v1.z);
        acc[6] += bf_lo(v1.w); acc[7] += bf_hi(v1.w);
    }
    if (j < dg) {
        int s0 = csr_src[start + j];
        uint4 v0 = *(const uint4*)(x + (size_t)s0 * D + lane * 8);
        acc[0] += bf_lo(v0.x); acc[1] += bf_hi(v0.x);
        acc[2] += bf_lo(v0.y); acc[3] += bf_hi(v0.y);
        acc[4] += bf_lo(v0.z); acc[5] += bf_hi(v0.z);
        acc[6] += bf_lo(v0.w); acc[7] += bf_hi(v0.w);
    }
    uint4 o;
    o.x = ((unsigned)f2bf(acc[1]) << 16) | f2bf(acc[0]);
    o.y = ((unsigned)f2bf(acc[3]) << 16) | f2bf(acc[2]);
    o.z = ((unsigned)f2bf(acc[5]) << 16) | f2bf(acc[4]);
    o.w = ((unsigned)f2bf(acc[7]) << 16) | f2bf(acc[6]);
    *(uint4*)(out + (size_t)g * D + lane * 8) = o;
}

// ===========================================================================
// Fused 2-layer MLP, bf16 MFMA (32x32x16), 64 rows/block, 4 waves.
// (unchanged from round 4/7 — verified correct, absmax 2.0)
// ===========================================================================
template<int LA, int LB, int LC, bool LSM>
__global__ __launch_bounds__(256)
void fused_mlp_mfma(const unsigned short* __restrict__ segA,
                    const unsigned short* __restrict__ segB,
                    const unsigned short* __restrict__ segC,
                    const unsigned short* __restrict__ WaT, const float* __restrict__ ba,
                    const unsigned short* __restrict__ WbT, const float* __restrict__ bb,
                    void* __restrict__ outv, int n) {
    constexpr int K1  = LA + LB + LC;       // 96 or 304
    constexpr int NS1 = K1 / 16;
    constexpr int K2P = 264;                // 256 + 8 (rows stay 16B-aligned)
    __shared__ __attribute__((aligned(16))) unsigned short hid[64 * K2P];

    const int tid  = threadIdx.x;
    const int wave = tid >> 6;
    const int lane = tid & 63;
    const int l31  = lane & 31;
    const int lh   = lane >> 5;
    const int row0 = blockIdx.x * 64;

    const int r0  = row0 + l31;
    const int r1  = r0 + 32;
    const int ra0 = (r0 < n) ? r0 : (n - 1);
    const int ra1 = (r1 < n) ? r1 : (n - 1);

    // ---------------- stage 1 ----------------
    f32x16 acc00 = {}, acc01 = {}, acc10 = {}, acc11 = {};
    const unsigned short* wa0 = WaT + (size_t)(wave * 64 + l31) * K1 + lh * 8;
    const unsigned short* wa1 = wa0 + (size_t)32 * K1;

    #pragma unroll
    for (int s = 0; s < NS1; ++s) {
        const int k0 = s * 16;              // compile-time; segment-uniform
        const unsigned short* ap;
        int strd, off;
        if (k0 < LA)           { ap = segA; strd = LA; off = k0; }
        else if (k0 < LA + LB) { ap = segB; strd = LB; off = k0 - LA; }
        else                   { ap = segC; strd = LC; off = k0 - LA - LB; }
        s16x8 a0 = *(const s16x8*)(ap + (size_t)ra0 * strd + off + lh * 8);
        s16x8 a1 = *(const s16x8*)(ap + (size_t)ra1 * strd + off + lh * 8);
        s16x8 b0 = *(const s16x8*)(wa0 + k0);
        s16x8 b1 = *(const s16x8*)(wa1 + k0);
        acc00 = __builtin_amdgcn_mfma_f32_32x32x16_bf16(a0, b0, acc00, 0, 0, 0);
        acc01 = __builtin_amdgcn_mfma_f32_32x32x16_bf16(a0, b1, acc01, 0, 0, 0);
        acc10 = __builtin_amdgcn_mfma_f32_32x32x16_bf16(a1, b0, acc10, 0, 0, 0);
        acc11 = __builtin_amdgcn_mfma_f32_32x32x16_bf16(a1, b1, acc11, 0, 0, 0);
    }

    // epilogue: + bias, relu -> hid[m][k] bf16
    {
        const int c0 = wave * 64 + l31;
        const int c1 = c0 + 32;
        const float bias0 = ba[c0];
        const float bias1 = ba[c1];
        #pragma unroll
        for (int t = 0; t < 16; ++t) {
            int rloc = (t & 3) + 8 * (t >> 2) + 4 * lh;
            hid[rloc * K2P + c0]        = f2bf(fmaxf(acc00[t] + bias0, 0.f));
            hid[rloc * K2P + c1]        = f2bf(fmaxf(acc01[t] + bias1, 0.f));
            hid[(rloc + 32) * K2P + c0] = f2bf(fmaxf(acc10[t] + bias0, 0.f));
            hid[(rloc + 32) * K2P + c1] = f2bf(fmaxf(acc11[t] + bias1, 0.f));
        }
    }
    __syncthreads();

    // ---------------- stage 2 ----------------
    if (!LSM) {
        f32x16 d0 = {}, d1 = {};
        const unsigned short* wb = WbT + (size_t)(wave * 32 + l31) * 256 + lh * 8;
        const int h0 = l31 * K2P + lh * 8;
        #pragma unroll
        for (int s = 0; s < 16; ++s) {
            s16x8 a0 = *(const s16x8*)&hid[h0 + s * 16];
            s16x8 a1 = *(const s16x8*)&hid[h0 + 32 * K2P + s * 16];
            s16x8 b  = *(const s16x8*)(wb + s * 16);
            d0 = __builtin_amdgcn_mfma_f32_32x32x16_bf16(a0, b, d0, 0, 0, 0);
            d1 = __builtin_amdgcn_mfma_f32_32x32x16_bf16(a1, b, d1, 0, 0, 0);
        }
        const int col = wave * 32 + l31;
        const float bias = bb[col];
        unsigned short* out = (unsigned short*)outv;
        #pragma unroll
        for (int t = 0; t < 16; ++t) {
            int rloc = (t & 3) + 8 * (t >> 2) + 4 * lh;
            int rr0 = row0 + rloc, rr1 = rr0 + 32;
            if (rr0 < n) out[(size_t)rr0 * 128 + col] = f2bf(fmaxf(d0[t] + bias, 0.f));
            if (rr1 < n) out[(size_t)rr1 * 128 + col] = f2bf(fmaxf(d1[t] + bias, 0.f));
        }
    } else {
        const int rt = wave & 1, ct = wave >> 1;
        f32x16 d = {};
        const unsigned short* wb = WbT + (size_t)(ct * 32 + l31) * 256 + lh * 8;
        const int h0 = (rt * 32 + l31) * K2P + lh * 8;
        #pragma unroll
        for (int s = 0; s < 16; ++s) {
            s16x8 a = *(const s16x8*)&hid[h0 + s * 16];
            s16x8 b = *(const s16x8*)(wb + s * 16);
            d = __builtin_amdgcn_mfma_f32_32x32x16_bf16(a, b, d, 0, 0, 0);
        }
        __syncthreads();                    // done reading hid; reuse as logits
        float* lg = (float*)hid;            // [64][68] f32 = 17.4KB <= 33.8KB
        const int col = ct * 32 + l31;
        const float bias = (col < 40) ? bb[col] : 0.f;
        #pragma unroll
        for (int t = 0; t < 16; ++t) {
            int rloc = rt * 32 + (t & 3) + 8 * (t >> 2) + 4 * lh;
            lg[rloc * 68 + col] = d[t] + bias;
        }
        __syncthreads();
        const int r = tid >> 2, j = tid & 3;
        float mx = -1e30f;
        #pragma unroll
        for (int c = 0; c < 10; ++c) mx = fmaxf(mx, lg[r * 68 + j * 10 + c]);
        mx = fmaxf(mx, __shfl_xor(mx, 1));
        mx = fmaxf(mx, __shfl_xor(mx, 2));
        float sm = 0.f;
        #pragma unroll
        for (int c = 0; c < 10; ++c) sm += __expf(lg[r * 68 + j * 10 + c] - mx);
        sm += __shfl_xor(sm, 1);
        sm += __shfl_xor(sm, 2);
        const float lse = mx + __logf(sm);
        const int row = row0 + r;
        float* out = (float*)outv;
        if (row < n) {
            #pragma unroll
            for (int c = 0; c < 10; ++c)
                out[(size_t)row * 40 + j * 10 + c] = lg[r * 68 + j * 10 + c] - lse;
        }
    }
}

// ===========================================================================
extern "C" void kernel_launch(void* const* d_in, const int* in_sizes, int n_in,
                              void* d_out, int out_size, void* d_ws, size_t ws_size,
                              hipStream_t stream) {
    const float* x   = (const float*)d_in[0];
    const int*   ei  = (const int*)d_in[1];
    const float* W1a = (const float*)d_in[2];
    const float* b1a = (const float*)d_in[3];
    const float* W1b = (const float*)d_in[4];
    const float* b1b = (const float*)d_in[5];
    const float* W2a = (const float*)d_in[6];
    const float* b2a = (const float*)d_in[7];
    const float* W2b = (const float*)d_in[8];
    const float* b2b = (const float*)d_in[9];
    const float* W3a = (const float*)d_in[10];
    const float* b3a = (const float*)d_in[11];
    const float* W3b = (const float*)d_in[12];
    const float* b3b = (const float*)d_in[13];
    float* out = (float*)d_out;

    const int E = in_sizes[1] / 2;
    const int N = in_sizes[0] / 48;
    const int* src = ei;
    const int* dst = ei + E;

    // ---- workspace carve-up (256B aligned) ----
    char* p = (char*)d_ws;
    auto alloc = [&](size_t bytes) { void* q = p; p += (bytes + 255) & ~(size_t)255; return q; };
    unsigned short* xbf  = (unsigned short*)alloc((size_t)N * 48  * 2);
    unsigned short* c1   = (unsigned short*)alloc((size_t)N * 48  * 2);
    unsigned short* h1   = (unsigned short*)alloc((size_t)N * 128 * 2);
    unsigned short* c2   = (unsigned short*)alloc((size_t)N * 128 * 2);  // also c3
    unsigned short* h2   = (unsigned short*)alloc((size_t)N * 128 * 2);
    unsigned short* W1aT = (unsigned short*)alloc((size_t)256 * 96  * 2);
    unsigned short* W1bT = (unsigned short*)alloc((size_t)128 * 256 * 2);
    unsigned short* W2aT = (unsigned short*)alloc((size_t)256 * 304 * 2);
    unsigned short* W2bT = (unsigned short*)alloc((size_t)128 * 256 * 2);
    unsigned short* W3aT = (unsigned short*)alloc((size_t)256 * 304 * 2);
    unsigned short* W3bT = (unsigned short*)alloc((size_t)64  * 256 * 2);
    int* deg     = (int*)alloc((size_t)N * 4);
    int* rowptr  = (int*)alloc((size_t)N * 4);
    int* cursor  = (int*)alloc((size_t)N * 4);
    int* bsum    = (int*)alloc(1024);
    int* csr_src = (int*)alloc((size_t)E * 4);

    const int nb_scan = (N + 1023) / 1024;
    const int nblk    = (N + 63) / 64;

    // ---- fused prep (x->bf16, 6 transposes, deg=0) ----
    {
        int total = N * 48 + N + 256*96 + 128*256 + 256*304 + 128*256 + 256*304 + 64*256;
        prep_fused<<<(total + 255) / 256, 256, 0, stream>>>(
            x, xbf, W1a, W1aT, W1b, W1bT, W2a, W2aT, W2b, W2bT,
            W3a, W3aT, W3b, W3bT, deg, N);
    }

    // ---- CSR build ----
    deg_hist_xcd<<<2048, 256, 0, stream>>>(dst, deg, E, N);
    scan_block_sums<<<nb_scan, 256, 0, stream>>>(deg, bsum, N);
    scan_bsums<<<1, 256, 0, stream>>>(bsum, nb_scan);
    scan_finalize<<<nb_scan, 256, 0, stream>>>(deg, bsum, rowptr, cursor, N);
    csr_scatter_xcd<<<2048, 256, 0, stream>>>(src, dst, cursor, csr_src, E, N);

    // ---- layer 1 ----
    lgconv_gather_bf16<48, 8><<<((size_t)N * 8 + 255) / 256, 256, 0, stream>>>(
        xbf, rowptr, deg, csr_src, c1, N);
    fused_mlp_mfma<48, 48, 0, false><<<nblk, 256, 0, stream>>>(
        c1, xbf, (const unsigned short*)nullptr, W1aT, b1a, W1bT, b1b, h1, N);

    // ---- layer 2 ----
    lgconv_gather_bf16<128, 16><<<((size_t)N * 16 + 255) / 256, 256, 0, stream>>>(
        h1, rowptr, deg, csr_src, c2, N);
    fused_mlp_mfma<128, 128, 48, false><<<nblk, 256, 0, stream>>>(
        c2, h1, xbf, W2aT, b2a, W2bT, b2b, h2, N);

    // ---- layer 3 ----
    lgconv_gather_bf16<128, 16><<<((size_t)N * 16 + 255) / 256, 256, 0, stream>>>(
        h2, rowptr, deg, csr_src, c2, N);   // c3 reuses c2 slot
    fused_mlp_mfma<128, 128, 48, true><<<nblk, 256, 0, stream>>>(
        c2, h2, xbf, W3aT, b3a, W3bT, b3b, out, N);
}

// Round 10
// 542.557 us; speedup vs baseline: 1.5649x; 1.0529x over previous
//
#include <hip/hip_runtime.h>
#include <math.h>

typedef __attribute__((ext_vector_type(8)))  short s16x8;   // 8 bf16 (4 VGPRs)
typedef __attribute__((ext_vector_type(16))) float f32x16;  // MFMA 32x32 acc

__device__ inline float bf_lo(unsigned u) { return __uint_as_float(u << 16); }
__device__ inline float bf_hi(unsigned u) { return __uint_as_float(u & 0xffff0000u); }
__device__ inline unsigned short f2bf(float f) {           // RNE f32 -> bf16
    unsigned u = __float_as_uint(f);
    u += 0x7fffu + ((u >> 16) & 1u);
    return (unsigned short)(u >> 16);
}

// ===========================================================================
// Fused prep: x f32->bf16, 6 weight transposes, deg zeroing. One dispatch.
// ===========================================================================
__global__ __launch_bounds__(256)
void prep_fused(const float* __restrict__ x,   unsigned short* __restrict__ xbf,
                const float* __restrict__ W1a, unsigned short* __restrict__ W1aT,
                const float* __restrict__ W1b, unsigned short* __restrict__ W1bT,
                const float* __restrict__ W2a, unsigned short* __restrict__ W2aT,
                const float* __restrict__ W2b, unsigned short* __restrict__ W2bT,
                const float* __restrict__ W3a, unsigned short* __restrict__ W3aT,
                const float* __restrict__ W3b, unsigned short* __restrict__ W3bT,
                int* __restrict__ deg, int N) {
    int i = blockIdx.x * 256 + threadIdx.x;
    int nx = N * 48;
    if (i < nx) { xbf[i] = f2bf(x[i]); return; }
    i -= nx;
    if (i < N) { deg[i] = 0; return; }
    i -= N;
    if (i < 256 * 96)  { int n = i / 96,  k = i - n * 96;  W1aT[i] = f2bf(W1a[(size_t)k * 256 + n]); return; }
    i -= 256 * 96;
    if (i < 128 * 256) { int n = i / 256, k = i - n * 256; W1bT[i] = f2bf(W1b[(size_t)k * 128 + n]); return; }
    i -= 128 * 256;
    if (i < 256 * 304) { int n = i / 304, k = i - n * 304; W2aT[i] = f2bf(W2a[(size_t)k * 256 + n]); return; }
    i -= 256 * 304;
    if (i < 128 * 256) { int n = i / 256, k = i - n * 256; W2bT[i] = f2bf(W2b[(size_t)k * 128 + n]); return; }
    i -= 128 * 256;
    if (i < 256 * 304) { int n = i / 304, k = i - n * 304; W3aT[i] = f2bf(W3a[(size_t)k * 256 + n]); return; }
    i -= 256 * 304;
    if (i < 64 * 256)  { int n = i / 256, k = i - n * 256;
                         float v = (n < 40) ? W3b[(size_t)k * 40 + n] : 0.f;
                         W3bT[i] = f2bf(v); return; }
}

// ===========================================================================
// CSR build (by dst), XCD-matched range ownership (verified round 9).
// ===========================================================================
__global__ __launch_bounds__(256)
void deg_hist_xcd(const int* __restrict__ dst, int* __restrict__ deg,
                  int E, int N) {
    const int r     = blockIdx.x & 7;
    const int sb    = blockIdx.x >> 3;
    const int nsl   = gridDim.x >> 3;
    const int chunk = (N + 7) / 8;
    const int lo = r * chunk;
    const int hi = min(lo + chunk, N);
    const int nq = E >> 2;
    const int4* dst4 = (const int4*)dst;
    for (int q = sb * 256 + threadIdx.x; q < nq; q += nsl * 256) {
        const int4 d4 = dst4[q];
        if (d4.x >= lo && d4.x < hi) atomicAdd(&deg[d4.x], 1);
        if (d4.y >= lo && d4.y < hi) atomicAdd(&deg[d4.y], 1);
        if (d4.z >= lo && d4.z < hi) atomicAdd(&deg[d4.z], 1);
        if (d4.w >= lo && d4.w < hi) atomicAdd(&deg[d4.w], 1);
    }
    if (sb == 0) {
        for (int e = nq * 4 + threadIdx.x; e < E; e += 256) {
            int d = dst[e];
            if (d >= lo && d < hi) atomicAdd(&deg[d], 1);
        }
    }
}

__global__ __launch_bounds__(256)
void scan_block_sums(const int* __restrict__ deg, int* __restrict__ bsum, int N) {
    __shared__ int sh[256];
    int base = blockIdx.x * 1024 + threadIdx.x * 4;
    int s = 0;
    #pragma unroll
    for (int k = 0; k < 4; ++k) { int i = base + k; if (i < N) s += deg[i]; }
    sh[threadIdx.x] = s;
    __syncthreads();
    for (int off = 128; off >= 1; off >>= 1) {
        if (threadIdx.x < off) sh[threadIdx.x] += sh[threadIdx.x + off];
        __syncthreads();
    }
    if (threadIdx.x == 0) bsum[blockIdx.x] = sh[0];
}

__global__ __launch_bounds__(256)
void scan_bsums(int* __restrict__ bsum, int nb) {
    __shared__ int sh[256];
    int t = threadIdx.x;
    int v = (t < nb) ? bsum[t] : 0;
    sh[t] = v;
    __syncthreads();
    for (int off = 1; off < 256; off <<= 1) {
        int add = (t >= off) ? sh[t - off] : 0;
        __syncthreads();
        sh[t] += add;
        __syncthreads();
    }
    if (t < nb) bsum[t] = sh[t] - v;
}

__global__ __launch_bounds__(256)
void scan_finalize(const int* __restrict__ deg, const int* __restrict__ bsum,
                   int* __restrict__ rowptr, int* __restrict__ cursor, int N) {
    __shared__ int sh[256];
    int t = threadIdx.x;
    int base = blockIdx.x * 1024 + t * 4;
    int loc[4];
    int s = 0;
    #pragma unroll
    for (int k = 0; k < 4; ++k) {
        int i = base + k;
        loc[k] = (i < N) ? deg[i] : 0;
        s += loc[k];
    }
    sh[t] = s;
    __syncthreads();
    for (int off = 1; off < 256; off <<= 1) {
        int add = (t >= off) ? sh[t - off] : 0;
        __syncthreads();
        sh[t] += add;
        __syncthreads();
    }
    int run = bsum[blockIdx.x] + sh[t] - s;
    #pragma unroll
    for (int k = 0; k < 4; ++k) {
        int i = base + k;
        if (i < N) { rowptr[i] = run; cursor[i] = run; }
        run += loc[k];
    }
}

__global__ __launch_bounds__(256)
void csr_scatter_xcd(const int* __restrict__ src, const int* __restrict__ dst,
                     int* __restrict__ cursor, int* __restrict__ csr_src,
                     int E, int N) {
    const int r     = blockIdx.x & 7;
    const int sb    = blockIdx.x >> 3;
    const int nsl   = gridDim.x >> 3;
    const int chunk = (N + 7) / 8;
    const int lo = r * chunk;
    const int hi = min(lo + chunk, N);
    const int nq = E >> 2;
    const int4* dst4 = (const int4*)dst;
    for (int q = sb * 256 + threadIdx.x; q < nq; q += nsl * 256) {
        const int4 d4 = dst4[q];
        const int e = q * 4;
        if (d4.x >= lo && d4.x < hi) { int p = atomicAdd(&cursor[d4.x], 1); if (p < E) csr_src[p] = src[e + 0]; }
        if (d4.y >= lo && d4.y < hi) { int p = atomicAdd(&cursor[d4.y], 1); if (p < E) csr_src[p] = src[e + 1]; }
        if (d4.z >= lo && d4.z < hi) { int p = atomicAdd(&cursor[d4.z], 1); if (p < E) csr_src[p] = src[e + 2]; }
        if (d4.w >= lo && d4.w < hi) { int p = atomicAdd(&cursor[d4.w], 1); if (p < E) csr_src[p] = src[e + 3]; }
    }
    if (sb == 0) {
        for (int e = nq * 4 + threadIdx.x; e < E; e += 256) {
            int d = dst[e];
            if (d >= lo && d < hi) { int p = atomicAdd(&cursor[d], 1); if (p < E) csr_src[p] = src[e]; }
        }
    }
}

// ===========================================================================
// LGConv gather, bf16 in/out, f32 accumulate. 8 channels (16B) per lane.
// ===========================================================================
template<int D, int LPN>
__global__ __launch_bounds__(256)
void lgconv_gather_bf16(const unsigned short* __restrict__ x,
                        const int* __restrict__ rowptr,
                        const int* __restrict__ deg,
                        const int* __restrict__ csr_src,
                        unsigned short* __restrict__ out, int N) {
    const int g    = (blockIdx.x * 256 + threadIdx.x) / LPN;
    const int lane = threadIdx.x & (LPN - 1);
    if (g >= N) return;
    if (lane * 8 >= D) return;
    const int start = rowptr[g];
    const int dg    = deg[g];
    float acc[8] = {0.f,0.f,0.f,0.f,0.f,0.f,0.f,0.f};
    int j = 0;
    for (; j + 1 < dg; j += 2) {
        int s0 = csr_src[start + j];
        int s1 = csr_src[start + j + 1];
        uint4 v0 = *(const uint4*)(x + (size_t)s0 * D + lane * 8);
        uint4 v1 = *(const uint4*)(x + (size_t)s1 * D + lane * 8);
        acc[0] += bf_lo(v0.x); acc[1] += bf_hi(v0.x);
        acc[2] += bf_lo(v0.y); acc[3] += bf_hi(v0.y);
        acc[4] += bf_lo(v0.z); acc[5] += bf_hi(v0.z);
        acc[6] += bf_lo(v0.w); acc[7] += bf_hi(v0.w);
        acc[0] += bf_lo(v1.x); acc[1] += bf_hi(v1.x);
        acc[2] += bf_lo(v1.y); acc[3] += bf_hi(v1.y);
        acc[4] += bf_lo(v1.z); acc[5] += bf_hi(v1.z);
        acc[6] += bf_lo(v1.w); acc[7] += bf_hi(v1.w);
    }
    if (j < dg) {
        int s0 = csr_src[start + j];
        uint4 v0 = *(const uint4*)(x + (size_t)s0 * D + lane * 8);
        acc[0] += bf_lo(v0.x); acc[1] += bf_hi(v0.x);
        acc[2] += bf_lo(v0.y); acc[3] += bf_hi(v0.y);
        acc[4] += bf_lo(v0.z); acc[5] += bf_hi(v0.z);
        acc[6] += bf_lo(v0.w); acc[7] += bf_hi(v0.w);
    }
    uint4 o;
    o.x = ((unsigned)f2bf(acc[1]) << 16) | f2bf(acc[0]);
    o.y = ((unsigned)f2bf(acc[3]) << 16) | f2bf(acc[2]);
    o.z = ((unsigned)f2bf(acc[5]) << 16) | f2bf(acc[4]);
    o.w = ((unsigned)f2bf(acc[7]) << 16) | f2bf(acc[6]);
    *(uint4*)(out + (size_t)g * D + lane * 8) = o;
}

// ===========================================================================
// Fused 2-layer MLP, bf16 MFMA (32x32x16), 64 rows/block, 4 waves.
// Round-10 change: A-tile staged in LDS via bulk coalesced uint4 loads
// (round-9 counters: MfmaUtil 12%, VALUBusy 11%, HBM 12% -> latency-bound on
// per-lane strided global A loads). A-tile UNIONS with hid (A dies exactly
// when hid is born) so LDS stays <=40KB -> 4 blocks/CU. Row pad K1+8 keeps
// 16B alignment; 4-way bank aliasing (1.58x) is the best 16B-aligned can do.
// ===========================================================================
template<int LA, int LB, int LC, bool LSM>
__global__ __launch_bounds__(256)
void fused_mlp_mfma(const unsigned short* __restrict__ segA,
                    const unsigned short* __restrict__ segB,
                    const unsigned short* __restrict__ segC,
                    const unsigned short* __restrict__ WaT, const float* __restrict__ ba,
                    const unsigned short* __restrict__ WbT, const float* __restrict__ bb,
                    void* __restrict__ outv, int n) {
    constexpr int K1   = LA + LB + LC;      // 96 or 304
    constexpr int NS1  = K1 / 16;
    constexpr int NCH  = K1 / 8;            // 16B chunks per row
    constexpr int KPAD = K1 + 8;            // 104 or 312 (16B-aligned rows)
    constexpr int K2P  = 264;               // hid row stride (bf16)
    constexpr int SW   = (64 * KPAD > 64 * K2P) ? 64 * KPAD : 64 * K2P;
    __shared__ __attribute__((aligned(16))) unsigned short smem[SW];
    unsigned short* Ab  = smem;             // stage-1 A tile   [64][KPAD]
    unsigned short* hid = smem;             // stage-1 out      [64][K2P] (union)

    const int tid  = threadIdx.x;
    const int wave = tid >> 6;
    const int lane = tid & 63;
    const int l31  = lane & 31;
    const int lh   = lane >> 5;
    const int row0 = blockIdx.x * 64;

    // ---- stage A tile: coalesced uint4, ~10 independent loads/thread ----
    for (int c = tid; c < 64 * NCH; c += 256) {
        const int m  = c / NCH;
        const int kc = c - m * NCH;
        const int row = row0 + m;
        const int ra  = (row < n) ? row : (n - 1);
        const unsigned short* sp;
        int koff;
        if (kc * 8 < LA)           { sp = segA + (size_t)ra * LA; koff = kc * 8; }
        else if (kc * 8 < LA + LB) { sp = segB + (size_t)ra * LB; koff = kc * 8 - LA; }
        else                       { sp = segC + (size_t)ra * LC; koff = kc * 8 - LA - LB; }
        *(uint4*)(Ab + m * KPAD + kc * 8) = *(const uint4*)(sp + koff);
    }
    __syncthreads();

    // ---------------- stage 1 ----------------
    f32x16 acc00 = {}, acc01 = {}, acc10 = {}, acc11 = {};
    const unsigned short* wa0 = WaT + (size_t)(wave * 64 + l31) * K1 + lh * 8;
    const unsigned short* wa1 = wa0 + (size_t)32 * K1;
    const int a0off = l31 * KPAD + lh * 8;
    const int a1off = (l31 + 32) * KPAD + lh * 8;

    #pragma unroll
    for (int s = 0; s < NS1; ++s) {
        const int k0 = s * 16;
        s16x8 a0 = *(const s16x8*)(Ab + a0off + k0);
        s16x8 a1 = *(const s16x8*)(Ab + a1off + k0);
        s16x8 b0 = *(const s16x8*)(wa0 + k0);
        s16x8 b1 = *(const s16x8*)(wa1 + k0);
        acc00 = __builtin_amdgcn_mfma_f32_32x32x16_bf16(a0, b0, acc00, 0, 0, 0);
        acc01 = __builtin_amdgcn_mfma_f32_32x32x16_bf16(a0, b1, acc01, 0, 0, 0);
        acc10 = __builtin_amdgcn_mfma_f32_32x32x16_bf16(a1, b0, acc10, 0, 0, 0);
        acc11 = __builtin_amdgcn_mfma_f32_32x32x16_bf16(a1, b1, acc11, 0, 0, 0);
    }
    __syncthreads();                        // all A reads done before hid overwrites

    // epilogue: + bias, relu -> hid[m][k] bf16 (C/D layout, m74/m101)
    {
        const int c0 = wave * 64 + l31;
        const int c1 = c0 + 32;
        const float bias0 = ba[c0];
        const float bias1 = ba[c1];
        #pragma unroll
        for (int t = 0; t < 16; ++t) {
            int rloc = (t & 3) + 8 * (t >> 2) + 4 * lh;
            hid[rloc * K2P + c0]        = f2bf(fmaxf(acc00[t] + bias0, 0.f));
            hid[rloc * K2P + c1]        = f2bf(fmaxf(acc01[t] + bias1, 0.f));
            hid[(rloc + 32) * K2P + c0] = f2bf(fmaxf(acc10[t] + bias0, 0.f));
            hid[(rloc + 32) * K2P + c1] = f2bf(fmaxf(acc11[t] + bias1, 0.f));
        }
    }
    __syncthreads();

    // ---------------- stage 2 ----------------
    if (!LSM) {
        f32x16 d0 = {}, d1 = {};
        const unsigned short* wb = WbT + (size_t)(wave * 32 + l31) * 256 + lh * 8;
        const int h0 = l31 * K2P + lh * 8;
        #pragma unroll
        for (int s = 0; s < 16; ++s) {
            s16x8 a0 = *(const s16x8*)&hid[h0 + s * 16];
            s16x8 a1 = *(const s16x8*)&hid[h0 + 32 * K2P + s * 16];
            s16x8 b  = *(const s16x8*)(wb + s * 16);
            d0 = __builtin_amdgcn_mfma_f32_32x32x16_bf16(a0, b, d0, 0, 0, 0);
            d1 = __builtin_amdgcn_mfma_f32_32x32x16_bf16(a1, b, d1, 0, 0, 0);
        }
        const int col = wave * 32 + l31;
        const float bias = bb[col];
        unsigned short* out = (unsigned short*)outv;
        #pragma unroll
        for (int t = 0; t < 16; ++t) {
            int rloc = (t & 3) + 8 * (t >> 2) + 4 * lh;
            int rr0 = row0 + rloc, rr1 = rr0 + 32;
            if (rr0 < n) out[(size_t)rr0 * 128 + col] = f2bf(fmaxf(d0[t] + bias, 0.f));
            if (rr1 < n) out[(size_t)rr1 * 128 + col] = f2bf(fmaxf(d1[t] + bias, 0.f));
        }
    } else {
        const int rt = wave & 1, ct = wave >> 1;
        f32x16 d = {};
        const unsigned short* wb = WbT + (size_t)(ct * 32 + l31) * 256 + lh * 8;
        const int h0 = (rt * 32 + l31) * K2P + lh * 8;
        #pragma unroll
        for (int s = 0; s < 16; ++s) {
            s16x8 a = *(const s16x8*)&hid[h0 + s * 16];
            s16x8 b = *(const s16x8*)(wb + s * 16);
            d = __builtin_amdgcn_mfma_f32_32x32x16_bf16(a, b, d, 0, 0, 0);
        }
        __syncthreads();                    // done reading hid; reuse as logits
        float* lg = (float*)smem;           // [64][68] f32 = 17.4KB
        const int col = ct * 32 + l31;
        const float bias = (col < 40) ? bb[col] : 0.f;
        #pragma unroll
        for (int t = 0; t < 16; ++t) {
            int rloc = rt * 32 + (t & 3) + 8 * (t >> 2) + 4 * lh;
            lg[rloc * 68 + col] = d[t] + bias;
        }
        __syncthreads();
        const int r = tid >> 2, j = tid & 3;
        float mx = -1e30f;
        #pragma unroll
        for (int c = 0; c < 10; ++c) mx = fmaxf(mx, lg[r * 68 + j * 10 + c]);
        mx = fmaxf(mx, __shfl_xor(mx, 1));
        mx = fmaxf(mx, __shfl_xor(mx, 2));
        float sm = 0.f;
        #pragma unroll
        for (int c = 0; c < 10; ++c) sm += __expf(lg[r * 68 + j * 10 + c] - mx);
        sm += __shfl_xor(sm, 1);
        sm += __shfl_xor(sm, 2);
        const float lse = mx + __logf(sm);
        const int row = row0 + r;
        float* out = (float*)outv;
        if (row < n) {
            #pragma unroll
            for (int c = 0; c < 10; ++c)
                out[(size_t)row * 40 + j * 10 + c] = lg[r * 68 + j * 10 + c] - lse;
        }
    }
}

// ===========================================================================
extern "C" void kernel_launch(void* const* d_in, const int* in_sizes, int n_in,
                              void* d_out, int out_size, void* d_ws, size_t ws_size,
                              hipStream_t stream) {
    const float* x   = (const float*)d_in[0];
    const int*   ei  = (const int*)d_in[1];
    const float* W1a = (const float*)d_in[2];
    const float* b1a = (const float*)d_in[3];
    const float* W1b = (const float*)d_in[4];
    const float* b1b = (const float*)d_in[5];
    const float* W2a = (const float*)d_in[6];
    const float* b2a = (const float*)d_in[7];
    const float* W2b = (const float*)d_in[8];
    const float* b2b = (const float*)d_in[9];
    const float* W3a = (const float*)d_in[10];
    const float* b3a = (const float*)d_in[11];
    const float* W3b = (const float*)d_in[12];
    const float* b3b = (const float*)d_in[13];
    float* out = (float*)d_out;

    const int E = in_sizes[1] / 2;
    const int N = in_sizes[0] / 48;
    const int* src = ei;
    const int* dst = ei + E;

    // ---- workspace carve-up (256B aligned) ----
    char* p = (char*)d_ws;
    auto alloc = [&](size_t bytes) { void* q = p; p += (bytes + 255) & ~(size_t)255; return q; };
    unsigned short* xbf  = (unsigned short*)alloc((size_t)N * 48  * 2);
    unsigned short* c1   = (unsigned short*)alloc((size_t)N * 48  * 2);
    unsigned short* h1   = (unsigned short*)alloc((size_t)N * 128 * 2);
    unsigned short* c2   = (unsigned short*)alloc((size_t)N * 128 * 2);  // also c3
    unsigned short* h2   = (unsigned short*)alloc((size_t)N * 128 * 2);
    unsigned short* W1aT = (unsigned short*)alloc((size_t)256 * 96  * 2);
    unsigned short* W1bT = (unsigned short*)alloc((size_t)128 * 256 * 2);
    unsigned short* W2aT = (unsigned short*)alloc((size_t)256 * 304 * 2);
    unsigned short* W2bT = (unsigned short*)alloc((size_t)128 * 256 * 2);
    unsigned short* W3aT = (unsigned short*)alloc((size_t)256 * 304 * 2);
    unsigned short* W3bT = (unsigned short*)alloc((size_t)64  * 256 * 2);
    int* deg     = (int*)alloc((size_t)N * 4);
    int* rowptr  = (int*)alloc((size_t)N * 4);
    int* cursor  = (int*)alloc((size_t)N * 4);
    int* bsum    = (int*)alloc(1024);
    int* csr_src = (int*)alloc((size_t)E * 4);

    const int nb_scan = (N + 1023) / 1024;
    const int nblk    = (N + 63) / 64;

    // ---- fused prep (x->bf16, 6 transposes, deg=0) ----
    {
        int total = N * 48 + N + 256*96 + 128*256 + 256*304 + 128*256 + 256*304 + 64*256;
        prep_fused<<<(total + 255) / 256, 256, 0, stream>>>(
            x, xbf, W1a, W1aT, W1b, W1bT, W2a, W2aT, W2b, W2bT,
            W3a, W3aT, W3b, W3bT, deg, N);
    }

    // ---- CSR build ----
    deg_hist_xcd<<<2048, 256, 0, stream>>>(dst, deg, E, N);
    scan_block_sums<<<nb_scan, 256, 0, stream>>>(deg, bsum, N);
    scan_bsums<<<1, 256, 0, stream>>>(bsum, nb_scan);
    scan_finalize<<<nb_scan, 256, 0, stream>>>(deg, bsum, rowptr, cursor, N);
    csr_scatter_xcd<<<2048, 256, 0, stream>>>(src, dst, cursor, csr_src, E, N);

    // ---- layer 1 ----
    lgconv_gather_bf16<48, 8><<<((size_t)N * 8 + 255) / 256, 256, 0, stream>>>(
        xbf, rowptr, deg, csr_src, c1, N);
    fused_mlp_mfma<48, 48, 0, false><<<nblk, 256, 0, stream>>>(
        c1, xbf, (const unsigned short*)nullptr, W1aT, b1a, W1bT, b1b, h1, N);

    // ---- layer 2 ----
    lgconv_gather_bf16<128, 16><<<((size_t)N * 16 + 255) / 256, 256, 0, stream>>>(
        h1, rowptr, deg, csr_src, c2, N);
    fused_mlp_mfma<128, 128, 48, false><<<nblk, 256, 0, stream>>>(
        c2, h1, xbf, W2aT, b2a, W2bT, b2b, h2, N);

    // ---- layer 3 ----
    lgconv_gather_bf16<128, 16><<<((size_t)N * 16 + 255) / 256, 256, 0, stream>>>(
        h2, rowptr, deg, csr_src, c2, N);   // c3 reuses c2 slot
    fused_mlp_mfma<128, 128, 48, true><<<nblk, 256, 0, stream>>>(
        c2, h2, xbf, W3aT, b3a, W3bT, b3b, out, N);
}